// Round 6
// baseline (390.084 us; speedup 1.0000x reference)
//
#include <hip/hip_runtime.h>
#include <cmath>

typedef __attribute__((ext_vector_type(8))) short bf16x8;
typedef __attribute__((ext_vector_type(4))) short bf16x4;
typedef __attribute__((ext_vector_type(4))) float f32x4;

constexpr int B_ = 4;
constexpr int S_ = 4096;
constexpr int DM_ = 1024;
constexpr int DK_ = 64;
constexpr int NROW = B_ * S_;   // 16384

__device__ __forceinline__ short f2bf(float x) {
  union { float f; unsigned u; } c; c.f = x;
  unsigned r = (c.u + 0x7FFF + ((c.u >> 16) & 1)) >> 16;  // RNE
  return (short)r;
}
__device__ __forceinline__ float bf2f(short h) {
  union { float f; unsigned u; } c; c.u = ((unsigned)(unsigned short)h) << 16;
  return c.f;
}

// ---------------------------------------------------------------------------
// Kernel 0: pack mask int32 -> bits, and convert Wq/Wk/Wv fp32 -> bf16.
// Blocks 0..1023: mask rows.  Blocks 1024..1026: W matrices.
// ---------------------------------------------------------------------------
__global__ __launch_bounds__(256) void prep(
    const int* __restrict__ mask, unsigned long long* __restrict__ bits,
    const float* __restrict__ Wq, const float* __restrict__ Wk,
    const float* __restrict__ Wv, short* __restrict__ wbf) {
  if (blockIdx.x < 1024) {
    const int wid = (blockIdx.x * 256 + threadIdx.x) >> 6;  // s row 0..4095
    const int lane = threadIdx.x & 63;
    const size_t base = (size_t)wid * 4096;
    for (int it = 0; it < 64; ++it) {
      int m = mask[base + it * 64 + lane];
      unsigned long long b = __ballot(m != 0);
      if (lane == 0) bits[(size_t)wid * 64 + it] = b;
    }
  } else {
    const int mat = blockIdx.x - 1024;
    const float* W = mat == 0 ? Wq : (mat == 1 ? Wk : Wv);
    short* dst = wbf + (size_t)mat * DK_ * DM_;
    const int t = threadIdx.x;
#pragma unroll 4
    for (int i = 0; i < 32; ++i) {
      int idx = i * 2048 + t * 8;
      f32x4 a0 = *(const f32x4*)(W + idx);
      f32x4 a1 = *(const f32x4*)(W + idx + 4);
      bf16x8 h;
#pragma unroll
      for (int j = 0; j < 4; ++j) { h[j] = f2bf(a0[j]); h[j + 4] = f2bf(a1[j]); }
      *(bf16x8*)(dst + idx) = h;
    }
  }
}

// ---------------------------------------------------------------------------
// Kernel 1: projections, bf16 MFMA, hi/lo split on X.  LDS-free, deep-
// pipelined register dataflow.
//   - __launch_bounds__(256, 3): VGPR cap ~168 (grid limits us to 12
//     waves/CU anyway) -- round-3's VGPR=48 starved the loop and forced
//     per-load waitcnt serialization (~1.2 TB/s Little's-law floor).
//   - K loop with #pragma unroll 4: ring indices ks&3 / (ks+3)&3 are
//     compile-time literals within each unrolled body (reg-resident ring)
//     while keeping code size ~4x smaller than a full unroll (de-risks
//     compile-time blowup suspected in rounds 4/5 container failures).
//   - 3-deep X prefetch ring; W loads issued at step top (L2-hot),
//     conversions+MFMA hide their latency.
// Fragment data / conversion / MFMA order identical to previous rounds ->
// bit-identical output.  qh/kh bf16 row-major; V transposed vhT[b][d][s].
// ---------------------------------------------------------------------------
__global__ __launch_bounds__(256, 3) void proj_mfma(
    const float* __restrict__ q, const float* __restrict__ k,
    const float* __restrict__ v, const short* __restrict__ wbf,
    const float* __restrict__ bq, const float* __restrict__ bk,
    const float* __restrict__ bv,
    short* __restrict__ qh, short* __restrict__ kh, short* __restrict__ vhT) {
  const int mat = blockIdx.z;
  const float* X    = mat == 0 ? q : (mat == 1 ? k : v);
  const short* W    = wbf + (size_t)mat * DK_ * DM_;
  const float* bias = mat == 0 ? bq : (mat == 1 ? bk : bv);

  const int t = threadIdx.x;
  const int row0 = blockIdx.x * 64;
  const int lane = t & 63, w = t >> 6, quad = lane >> 4, l16 = lane & 15;

  const int myrow = row0 + 16 * w + l16;
  const float* xp = X + (size_t)myrow * DM_ + quad * 8;   // + ks*64 + {0,4,32,36}
  const short* wp0 = W + (size_t)l16 * DM_ + quad * 8;    // ct=0 base
  const short* wp1 = wp0 + 16 * DM_;
  const short* wp2 = wp0 + 32 * DM_;
  const short* wp3 = wp0 + 48 * DM_;

  f32x4 acc[4] = {};
  f32x4 xr[4][4];   // 3-deep prefetch ring (slot rotates through 4)

  // ---- prologue: prefetch X for steps 0,1,2
#pragma unroll
  for (int pb = 0; pb < 3; ++pb) {
    const float* s = xp + pb * 64;
    xr[pb][0] = *(const f32x4*)(s + 0);
    xr[pb][1] = *(const f32x4*)(s + 4);
    xr[pb][2] = *(const f32x4*)(s + 32);
    xr[pb][3] = *(const f32x4*)(s + 36);
  }

#pragma unroll 4
  for (int ks = 0; ks < 16; ++ks) {
    // ---- prefetch X for step ks+3 (3 steps ahead); (ks+3)&3 is a
    //      compile-time literal inside each unroll-4 body
    if (ks < 13) {
      const float* s = xp + (ks + 3) * 64;
      xr[(ks + 3) & 3][0] = *(const f32x4*)(s + 0);
      xr[(ks + 3) & 3][1] = *(const f32x4*)(s + 4);
      xr[(ks + 3) & 3][2] = *(const f32x4*)(s + 32);
      xr[(ks + 3) & 3][3] = *(const f32x4*)(s + 36);
    }

    // ---- W fragments for this step (L2-hot; latency hidden by the
    //      conversion VALU below)
    bf16x8 wf[2][4];
#pragma unroll
    for (int c = 0; c < 2; ++c) {
      wf[c][0] = *(const bf16x8*)(wp0 + ks * 64 + c * 32);
      wf[c][1] = *(const bf16x8*)(wp1 + ks * 64 + c * 32);
      wf[c][2] = *(const bf16x8*)(wp2 + ks * 64 + c * 32);
      wf[c][3] = *(const bf16x8*)(wp3 + ks * 64 + c * 32);
    }

    // ---- compute (identical data/order as before -> bit-identical)
#pragma unroll
    for (int c = 0; c < 2; ++c) {
      f32x4 x0 = xr[ks & 3][2 * c + 0];
      f32x4 x1 = xr[ks & 3][2 * c + 1];
      bf16x8 ahi, alo;
#pragma unroll
      for (int j = 0; j < 4; ++j) {
        short h0 = f2bf(x0[j]); ahi[j] = h0;     alo[j]     = f2bf(x0[j] - bf2f(h0));
        short h1 = f2bf(x1[j]); ahi[j + 4] = h1; alo[j + 4] = f2bf(x1[j] - bf2f(h1));
      }
#pragma unroll
      for (int ct = 0; ct < 4; ++ct) {
        acc[ct] = __builtin_amdgcn_mfma_f32_16x16x32_bf16(ahi, wf[c][ct], acc[ct], 0, 0, 0);
        acc[ct] = __builtin_amdgcn_mfma_f32_16x16x32_bf16(alo, wf[c][ct], acc[ct], 0, 0, 0);
      }
    }
  }

  float bs[4];
#pragma unroll
  for (int ct = 0; ct < 4; ++ct) bs[ct] = bias[16 * ct + l16];

  short* dstq = (mat == 0) ? qh : kh;
#pragma unroll
  for (int ct = 0; ct < 4; ++ct)
#pragma unroll
    for (int reg = 0; reg < 4; ++reg) {
      int r = row0 + 16 * w + quad * 4 + reg;
      int c = 16 * ct + l16;
      short hv = f2bf(acc[ct][reg] + bs[ct]);
      if (mat == 2)
        vhT[((size_t)(r >> 12) * DK_ + c) * S_ + (r & 4095)] = hv;
      else
        dstq[(size_t)r * DK_ + c] = hv;
    }
}

// ---------------------------------------------------------------------------
// Kernel 2: split-K flash attention, bf16 MFMA, transposed formulation.
// ---------------------------------------------------------------------------
__global__ __launch_bounds__(256) void attn_mfma(
    const short* __restrict__ qh, const short* __restrict__ kh,
    const short* __restrict__ vhT, const unsigned int* __restrict__ mbits,
    float* __restrict__ Opart, float* __restrict__ mpart,
    float* __restrict__ lpart, int ns) {
  __shared__ short ks[64][72];
  __shared__ short vt[64][72];
  __shared__ short ps[4][16][72];

  const int b = blockIdx.z;
  const int split = blockIdx.y;
  const int q0 = blockIdx.x * 64;
  const int t = threadIdx.x, lane = t & 63, w = t >> 6;
  const int quad = lane >> 4, l16 = lane & 15;
  const int myq = q0 + 16 * w + l16;

  const int kt0 = split * (S_ / ns);
  const int kt1 = kt0 + S_ / ns;

  bf16x8 qf[2];
  {
    const short* src = qh + ((size_t)b * S_ + myq) * DK_ + quad * 8;
    qf[0] = *(const bf16x8*)src;
    qf[1] = *(const bf16x8*)(src + 32);
  }

  f32x4 ao[4] = {};
  float m_i = -INFINITY, l_i = 0.0f;

  const int sr = t >> 2;        // staging row 0..63
  const int sseg = t & 3;       // 16B segments sseg, sseg+4

  for (int kt = kt0; kt < kt1; kt += 64) {
    __syncthreads();
    {
      const short* srck = kh + ((size_t)b * S_ + kt + sr) * DK_;
      *(bf16x8*)&ks[sr][8 * sseg]       = *(const bf16x8*)(srck + 8 * sseg);
      *(bf16x8*)&ks[sr][8 * (sseg + 4)] = *(const bf16x8*)(srck + 8 * (sseg + 4));
      const short* srcv = vhT + ((size_t)b * DK_ + sr) * S_ + kt;
      *(bf16x8*)&vt[sr][8 * sseg]       = *(const bf16x8*)(srcv + 8 * sseg);
      *(bf16x8*)&vt[sr][8 * (sseg + 4)] = *(const bf16x8*)(srcv + 8 * (sseg + 4));
    }
    const uint2 mw = *(const uint2*)&mbits[(size_t)myq * 128 + (kt >> 5)];
    __syncthreads();

    // S^T = K . Q^T
    f32x4 sacc[4] = {};
#pragma unroll
    for (int c = 0; c < 2; ++c)
#pragma unroll
      for (int tt = 0; tt < 4; ++tt) {
        bf16x8 a = *(const bf16x8*)&ks[16 * tt + l16][c * 32 + quad * 8];
        sacc[tt] = __builtin_amdgcn_mfma_f32_16x16x32_bf16(a, qf[c], sacc[tt], 0, 0, 0);
      }

    // mask + scale
    float sc[16];
#pragma unroll
    for (int tt = 0; tt < 4; ++tt) {
      unsigned wrd = (tt & 2) ? mw.y : mw.x;
      int base = (tt & 1) * 16 + quad * 4;
#pragma unroll
      for (int r = 0; r < 4; ++r)
        sc[tt * 4 + r] = ((wrd >> (base + r)) & 1) ? sacc[tt][r] * 0.125f : -1e9f;
    }

    // per-lane online softmax (lane owns one q-col)
    float mx = sc[0];
#pragma unroll
    for (int i = 1; i < 16; ++i) mx = fmaxf(mx, sc[i]);
    mx = fmaxf(mx, __shfl_xor(mx, 16));
    mx = fmaxf(mx, __shfl_xor(mx, 32));
    float m_new = fmaxf(m_i, mx);
    float alpha = __expf(m_i - m_new);   // first iter: exp(-inf)=0
    float p[16], sum = 0.0f;
#pragma unroll
    for (int i = 0; i < 16; ++i) { p[i] = __expf(sc[i] - m_new); sum += p[i]; }
    sum += __shfl_xor(sum, 16);
    sum += __shfl_xor(sum, 32);
    l_i = l_i * alpha + sum;
    m_i = m_new;

    // P^T -> LDS bf16
#pragma unroll
    for (int tt = 0; tt < 4; ++tt) {
      bf16x4 pk;
#pragma unroll
      for (int r = 0; r < 4; ++r) pk[r] = f2bf(p[tt * 4 + r]);
      *(bf16x4*)&ps[w][l16][16 * tt + quad * 4] = pk;
    }

#pragma unroll
    for (int dt = 0; dt < 4; ++dt)
#pragma unroll
      for (int r = 0; r < 4; ++r) ao[dt][r] *= alpha;

    // O^T += V^T . P^T
#pragma unroll
    for (int c = 0; c < 2; ++c) {
      bf16x8 bp = *(const bf16x8*)&ps[w][l16][c * 32 + quad * 8];
#pragma unroll
      for (int dt = 0; dt < 4; ++dt) {
        bf16x8 av = *(const bf16x8*)&vt[16 * dt + l16][c * 32 + quad * 8];
        ao[dt] = __builtin_amdgcn_mfma_f32_16x16x32_bf16(av, bp, ao[dt], 0, 0, 0);
      }
    }
  }

  const size_t prow = (size_t)split * NROW + (size_t)b * S_ + myq;
#pragma unroll
  for (int dt = 0; dt < 4; ++dt)
    *(f32x4*)&Opart[prow * DK_ + 16 * dt + quad * 4] = ao[dt];
  if (quad == 0) {
    mpart[prow] = m_i;
    lpart[prow] = l_i;
  }
}

// ---------------------------------------------------------------------------
// Kernel 2b: combine split partials -> o bf16.
// ---------------------------------------------------------------------------
__global__ __launch_bounds__(256) void attn_combine(
    const float* __restrict__ Opart, const float* __restrict__ mpart,
    const float* __restrict__ lpart, short* __restrict__ o_bf, int ns) {
  const int t = threadIdx.x;
  const int row = blockIdx.x * 64 + (t >> 2);
  const int c0 = (t & 3) * 16;

  float M = -INFINITY;
  for (int s = 0; s < ns; ++s) M = fmaxf(M, mpart[(size_t)s * NROW + row]);
  float L = 0.0f, wt[4];
  for (int s = 0; s < ns; ++s) {
    wt[s] = __expf(mpart[(size_t)s * NROW + row] - M);
    L += wt[s] * lpart[(size_t)s * NROW + row];
  }
  float acc[16] = {};
  for (int s = 0; s < ns; ++s) {
    const float* src = Opart + ((size_t)s * NROW + row) * DK_ + c0;
#pragma unroll
    for (int j = 0; j < 16; j += 4) {
      f32x4 vv = *(const f32x4*)(src + j);
#pragma unroll
      for (int r = 0; r < 4; ++r) acc[j + r] += wt[s] * vv[r];
    }
  }
  const float inv = 1.0f / L;
  bf16x8 o0, o1;
#pragma unroll
  for (int j = 0; j < 8; ++j) {
    o0[j] = f2bf(acc[j] * inv);
    o1[j] = f2bf(acc[j + 8] * inv);
  }
  *(bf16x8*)&o_bf[(size_t)row * DK_ + c0]     = o0;
  *(bf16x8*)&o_bf[(size_t)row * DK_ + c0 + 8] = o1;
}

// ---------------------------------------------------------------------------
// Kernel 3: output projection, bf16 MFMA.  Tile 64 s x 256 dm, K=64.
// ---------------------------------------------------------------------------
__global__ __launch_bounds__(256) void outproj_mfma(
    const short* __restrict__ o_bf, const float* __restrict__ Wo,
    const float* __restrict__ bo, float* __restrict__ out) {
  __shared__ short os[64][72];
  __shared__ short wos[256][72];

  const int t = threadIdx.x, lane = t & 63, w = t >> 6;
  const int quad = lane >> 4, l16 = lane & 15;
  const int s0 = blockIdx.y * 64;
  const int dm0 = blockIdx.x * 256;

  {  // stage o (bf16 copy)
    int r = t >> 2, cq = (t & 3) * 16;
    const short* src = o_bf + (size_t)(s0 + r) * DK_ + cq;
    *(bf16x8*)&os[r][cq]     = *(const bf16x8*)src;
    *(bf16x8*)&os[r][cq + 8] = *(const bf16x8*)(src + 8);
  }
#pragma unroll
  for (int pass = 0; pass < 4; ++pass) {  // stage Wo tile 256x64 fp32->bf16
    int r = pass * 64 + (t >> 2), cq = (t & 3) * 16;
    const float* src = Wo + (size_t)(dm0 + r) * DK_ + cq;
    f32x4 a0 = *(const f32x4*)src, a1 = *(const f32x4*)(src + 4);
    f32x4 a2 = *(const f32x4*)(src + 8), a3 = *(const f32x4*)(src + 12);
    bf16x8 v0, v1;
#pragma unroll
    for (int j = 0; j < 4; ++j) {
      v0[j] = f2bf(a0[j]); v0[j + 4] = f2bf(a1[j]);
      v1[j] = f2bf(a2[j]); v1[j + 4] = f2bf(a3[j]);
    }
    *(bf16x8*)&wos[r][cq]     = v0;
    *(bf16x8*)&wos[r][cq + 8] = v1;
  }
  __syncthreads();

  bf16x8 af[2];
#pragma unroll
  for (int c = 0; c < 2; ++c)
    af[c] = *(const bf16x8*)&os[16 * w + l16][c * 32 + quad * 8];

  f32x4 acc[16] = {};
#pragma unroll
  for (int c = 0; c < 2; ++c)
#pragma unroll
    for (int nt = 0; nt < 16; ++nt) {
      bf16x8 bw = *(const bf16x8*)&wos[16 * nt + l16][c * 32 + quad * 8];
      acc[nt] = __builtin_amdgcn_mfma_f32_16x16x32_bf16(af[c], bw, acc[nt], 0, 0, 0);
    }

  float bias_r[16];
#pragma unroll
  for (int nt = 0; nt < 16; ++nt) bias_r[nt] = bo[dm0 + 16 * nt + l16];

#pragma unroll
  for (int nt = 0; nt < 16; ++nt)
#pragma unroll
    for (int reg = 0; reg < 4; ++reg) {
      int s = s0 + 16 * w + quad * 4 + reg;
      int dm = dm0 + 16 * nt + l16;
      out[(size_t)s * DM_ + dm] = acc[nt][reg] + bias_r[nt];
    }
}

// ---------------------------------------------------------------------------
extern "C" void kernel_launch(void* const* d_in, const int* in_sizes, int n_in,
                              void* d_out, int out_size, void* d_ws,
                              size_t ws_size, hipStream_t stream) {
  (void)in_sizes; (void)n_in; (void)out_size;
  const float* q  = (const float*)d_in[0];
  const float* k  = (const float*)d_in[1];
  const float* v  = (const float*)d_in[2];
  const int* mask = (const int*)d_in[3];
  const float* Wq = (const float*)d_in[4];
  const float* bq = (const float*)d_in[5];
  const float* Wk = (const float*)d_in[6];
  const float* bk = (const float*)d_in[7];
  const float* Wv = (const float*)d_in[8];
  const float* bv = (const float*)d_in[9];
  const float* Wo = (const float*)d_in[10];
  const float* bo = (const float*)d_in[11];
  float* out = (float*)d_out;

  // ws layout: qh 2MB | kh 2MB | vhT 2MB | mbits 2MB | o_bf 2MB |
  //            mpart 256KB | lpart 256KB | Opart ns*4MB
  short* qh  = (short*)d_ws;
  short* kh  = qh + (size_t)NROW * DK_;
  short* vhT = kh + (size_t)NROW * DK_;
  unsigned int* mbits = (unsigned int*)(vhT + (size_t)NROW * DK_);
  short* o_bf = (short*)(mbits + (size_t)S_ * 128);
  float* mpart = (float*)(o_bf + (size_t)NROW * DK_);
  float* lpart = mpart + 4 * NROW;           // reserved for ns up to 4
  float* Opart = lpart + 4 * NROW;
  // Wbf (3 x 64 x 1024 bf16 = 384 KB) aliases the head of Opart: prep writes
  // it, proj reads it, and only AFTER proj does attn_mfma overwrite Opart.
  short* wbf = (short*)Opart;

  const size_t base_bytes = (size_t)((char*)Opart - (char*)d_ws);
  const size_t per_split = (size_t)NROW * DK_ * sizeof(float);   // 4 MB
  int ns = 1;
  if (ws_size >= base_bytes + 4 * per_split) ns = 4;
  else if (ws_size >= base_bytes + 2 * per_split) ns = 2;

  prep<<<1027, 256, 0, stream>>>(mask, (unsigned long long*)mbits,
                                 Wq, Wk, Wv, wbf);
  proj_mfma<<<dim3(NROW / 64, 1, 3), 256, 0, stream>>>(
      q, k, v, wbf, bq, bk, bv, qh, kh, vhT);
  attn_mfma<<<dim3(S_ / 64, ns, B_), 256, 0, stream>>>(
      qh, kh, vhT, mbits, Opart, mpart, lpart, ns);
  attn_combine<<<NROW / 64, 256, 0, stream>>>(Opart, mpart, lpart, o_bf, ns);
  outproj_mfma<<<dim3(DM_ / 256, NROW / 64), 256, 0, stream>>>(o_bf, Wo, bo, out);
}

// Round 7
// 373.041 us; speedup vs baseline: 1.0457x; 1.0457x over previous
//
#include <hip/hip_runtime.h>
#include <cmath>

typedef __attribute__((ext_vector_type(8))) short bf16x8;
typedef __attribute__((ext_vector_type(4))) short bf16x4;
typedef __attribute__((ext_vector_type(4))) float f32x4;
typedef unsigned int u32;
typedef __attribute__((address_space(1))) const u32 gu32;
typedef __attribute__((address_space(3))) u32 lu32;

constexpr int B_ = 4;
constexpr int S_ = 4096;
constexpr int DM_ = 1024;
constexpr int DK_ = 64;
constexpr int NROW = B_ * S_;   // 16384

__device__ __forceinline__ short f2bf(float x) {
  union { float f; unsigned u; } c; c.f = x;
  unsigned r = (c.u + 0x7FFF + ((c.u >> 16) & 1)) >> 16;  // RNE
  return (short)r;
}
__device__ __forceinline__ float bf2f(short h) {
  union { float f; unsigned u; } c; c.u = ((unsigned)(unsigned short)h) << 16;
  return c.f;
}
__device__ __forceinline__ void gl16(const void* g, void* l) {
  __builtin_amdgcn_global_load_lds((gu32*)g, (lu32*)l, 16, 0, 0);
}

// ---------------------------------------------------------------------------
// Kernel 0: pack mask int32 -> bits, and convert Wq/Wk/Wv fp32 -> bf16.
// Blocks 0..1023: mask rows.  Blocks 1024..1026: W matrices.
// ---------------------------------------------------------------------------
__global__ __launch_bounds__(256) void prep(
    const int* __restrict__ mask, unsigned long long* __restrict__ bits,
    const float* __restrict__ Wq, const float* __restrict__ Wk,
    const float* __restrict__ Wv, short* __restrict__ wbf) {
  if (blockIdx.x < 1024) {
    const int wid = (blockIdx.x * 256 + threadIdx.x) >> 6;  // s row 0..4095
    const int lane = threadIdx.x & 63;
    const size_t base = (size_t)wid * 4096;
    for (int it = 0; it < 64; ++it) {
      int m = mask[base + it * 64 + lane];
      unsigned long long b = __ballot(m != 0);
      if (lane == 0) bits[(size_t)wid * 64 + it] = b;
    }
  } else {
    const int mat = blockIdx.x - 1024;
    const float* W = mat == 0 ? Wq : (mat == 1 ? Wk : Wv);
    short* dst = wbf + (size_t)mat * DK_ * DM_;
    const int t = threadIdx.x;
#pragma unroll 4
    for (int i = 0; i < 32; ++i) {
      int idx = i * 2048 + t * 8;
      f32x4 a0 = *(const f32x4*)(W + idx);
      f32x4 a1 = *(const f32x4*)(W + idx + 4);
      bf16x8 h;
#pragma unroll
      for (int j = 0; j < 4; ++j) { h[j] = f2bf(a0[j]); h[j + 4] = f2bf(a1[j]); }
      *(bf16x8*)(dst + idx) = h;
    }
  }
}

// ---------------------------------------------------------------------------
// Kernel 1: projections, bf16 MFMA, hi/lo split on X.
// MODEL (fits rounds 0/2/3/6): the per-CU vector-memory path (~10 B/cyc/CU,
// 6.3 TB/s aggregate) counts ALL vmem traffic, L2-hit or not.  Rounds 3/6
// moved 590 MB (X 196 + W re-loaded per-wave 393) -> path-saturated at
// ~6 TB/s = ~95 us.  Round 2 moved 294 MB but full vmcnt(0) drains at each
// __syncthreads serialized it.  This version:
//   - W staged ONCE PER BLOCK per K-step into 16 KB double-buffered LDS via
//     global_load_lds (98 MB total); per-wave fragment reads go through the
//     DS pipe (128 B/cyc/CU) with the round-2-verified XOR swizzle
//     (both-sides: pre-swizzled global source + swizzled ds_read, 2-way=free)
//   - X per-lane direct global->reg, 2-step prefetch ring
//   - raw s_barrier + counted s_waitcnt vmcnt(4) (never 0 in steady state:
//     W(i+1) landed, X(i+2) stays in flight); vmcnt(0) only in 2-step tail
// vmem bytes 590 -> 294 MB.  Fragment bytes / conversion / MFMA order
// bit-identical to all previous rounds.  qh/kh row-major; vhT[b][d][s].
// ---------------------------------------------------------------------------
__global__ __launch_bounds__(256, 3) void proj_mfma(
    const float* __restrict__ q, const float* __restrict__ k,
    const float* __restrict__ v, const short* __restrict__ wbf,
    const float* __restrict__ bq, const float* __restrict__ bk,
    const float* __restrict__ bv,
    short* __restrict__ qh, short* __restrict__ kh, short* __restrict__ vhT) {
  __shared__ short wlds[2][64][64];   // [buf][row][64 bf16 cols] = 16 KB

  const int mat = blockIdx.z;
  const float* X    = mat == 0 ? q : (mat == 1 ? k : v);
  const short* W    = wbf + (size_t)mat * DK_ * DM_;
  const float* bias = mat == 0 ? bq : (mat == 1 ? bk : bv);

  const int t = threadIdx.x;
  const int row0 = blockIdx.x * 64;
  const int lane = t & 63, w = t >> 6, quad = lane >> 4, l16 = lane & 15;

  // X per-lane base: row 16w+l16, cols quad*8 (+ ks*64 + c*32)
  const int myrow = row0 + 16 * w + l16;
  const float* xp = X + (size_t)myrow * DM_ + quad * 8;

  // W staging (per wave j=0,1): dest rows 16w+8j..+7, linear LDS;
  // global source pre-swizzled so that LDS[row][colb] holds
  // W[row][ks*128 + (colb ^ ((row&7)<<4))] (byte addressing within 128B row).
  const int grA = 16 * w + (lane >> 3);            // j=0 row
  const int scolh = (((lane & 7) ^ (lane >> 3)) * 8);  // shorts
  const short* wsrcA = W + (size_t)grA * DM_ + scolh;          // + ks*64
  const short* wsrcB = W + (size_t)(grA + 8) * DM_ + scolh;    // j=1
  short* wdstA0 = &wlds[0][16 * w][0] + lane * 8;
  short* wdstB0 = &wlds[0][16 * w + 8][0] + lane * 8;
  short* wdstA1 = &wlds[1][16 * w][0] + lane * 8;
  short* wdstB1 = &wlds[1][16 * w + 8][0] + lane * 8;

  // swizzled ds_read byte offsets for the 8 fragments (c in 0..1, ct in 0..3)
  const int rsw = (l16 & 7) << 4;

  f32x4 acc[4] = {};
  f32x4 xr[4][4];   // prefetch ring, 2 steps ahead (slots via &3)

  // ---- prologue: stage W(0) into buf0; prefetch X(0), X(1)
  gl16(wsrcA, wdstA0);
  gl16(wsrcB, wdstB0);
#pragma unroll
  for (int pb = 0; pb < 2; ++pb) {
    const float* s = xp + pb * 64;
    xr[pb][0] = *(const f32x4*)(s + 0);
    xr[pb][1] = *(const f32x4*)(s + 4);
    xr[pb][2] = *(const f32x4*)(s + 32);
    xr[pb][3] = *(const f32x4*)(s + 36);
  }
  asm volatile("s_waitcnt vmcnt(8)" ::: "memory");  // W(0) done (8 X newer)
  __builtin_amdgcn_s_barrier();
  __builtin_amdgcn_sched_barrier(0);

  // ---- one K-step body (compute step i from buf, using ring slot i&3)
  auto compute_step = [&](int i, int buf) {
    const char* wb = (const char*)&wlds[buf][0][0];
    bf16x8 wf[2][4];
#pragma unroll
    for (int c = 0; c < 2; ++c)
#pragma unroll
      for (int ct = 0; ct < 4; ++ct)
        wf[c][ct] = *(const bf16x8*)(wb + (16 * ct + l16) * 128 +
                                     ((c * 64 + quad * 16) ^ rsw));
#pragma unroll
    for (int c = 0; c < 2; ++c) {
      f32x4 x0 = xr[i & 3][2 * c + 0];
      f32x4 x1 = xr[i & 3][2 * c + 1];
      bf16x8 ahi, alo;
#pragma unroll
      for (int j = 0; j < 4; ++j) {
        short h0 = f2bf(x0[j]); ahi[j] = h0;     alo[j]     = f2bf(x0[j] - bf2f(h0));
        short h1 = f2bf(x1[j]); ahi[j + 4] = h1; alo[j + 4] = f2bf(x1[j] - bf2f(h1));
      }
#pragma unroll
      for (int ct = 0; ct < 4; ++ct) {
        acc[ct] = __builtin_amdgcn_mfma_f32_16x16x32_bf16(ahi, wf[c][ct], acc[ct], 0, 0, 0);
        acc[ct] = __builtin_amdgcn_mfma_f32_16x16x32_bf16(alo, wf[c][ct], acc[ct], 0, 0, 0);
      }
    }
  };

  // ---- main loop: steps 0..11 (steady state, counted vmcnt)
#pragma unroll 4
  for (int i = 0; i < 12; ++i) {
    const int nb = (i + 1) & 1;
    // stage W(i+1) into the other buffer (its readers finished last step)
    gl16(wsrcA + (i + 1) * 64, nb ? wdstA1 : wdstA0);
    gl16(wsrcB + (i + 1) * 64, nb ? wdstB1 : wdstB0);
    // prefetch X(i+2)
    {
      const float* s = xp + (i + 2) * 64;
      xr[(i + 2) & 3][0] = *(const f32x4*)(s + 0);
      xr[(i + 2) & 3][1] = *(const f32x4*)(s + 4);
      xr[(i + 2) & 3][2] = *(const f32x4*)(s + 32);
      xr[(i + 2) & 3][3] = *(const f32x4*)(s + 36);
    }
    compute_step(i, i & 1);
    // W(i+1) done (only X(i+2)'s 4 loads are newer); X(i+2) stays in flight
    asm volatile("s_waitcnt vmcnt(4)" ::: "memory");
    __builtin_amdgcn_s_barrier();
    __builtin_amdgcn_sched_barrier(0);
  }

  // ---- tail: steps 12..15 (literal indices; drain at 14)
  // step 12: stage W(13), prefetch X(14)
  gl16(wsrcA + 13 * 64, wdstA1);
  gl16(wsrcB + 13 * 64, wdstB1);
  {
    const float* s = xp + 14 * 64;
    xr[2][0] = *(const f32x4*)(s + 0);  xr[2][1] = *(const f32x4*)(s + 4);
    xr[2][2] = *(const f32x4*)(s + 32); xr[2][3] = *(const f32x4*)(s + 36);
  }
  compute_step(12, 0);
  asm volatile("s_waitcnt vmcnt(4)" ::: "memory");
  __builtin_amdgcn_s_barrier();
  __builtin_amdgcn_sched_barrier(0);
  // step 13: stage W(14), prefetch X(15)
  gl16(wsrcA + 14 * 64, wdstA0);
  gl16(wsrcB + 14 * 64, wdstB0);
  {
    const float* s = xp + 15 * 64;
    xr[3][0] = *(const f32x4*)(s + 0);  xr[3][1] = *(const f32x4*)(s + 4);
    xr[3][2] = *(const f32x4*)(s + 32); xr[3][3] = *(const f32x4*)(s + 36);
  }
  compute_step(13, 1);
  asm volatile("s_waitcnt vmcnt(4)" ::: "memory");
  __builtin_amdgcn_s_barrier();
  __builtin_amdgcn_sched_barrier(0);
  // step 14: stage W(15), no X left -> drain before barrier
  gl16(wsrcA + 15 * 64, wdstA1);
  gl16(wsrcB + 15 * 64, wdstB1);
  compute_step(14, 0);
  asm volatile("s_waitcnt vmcnt(0)" ::: "memory");
  __builtin_amdgcn_s_barrier();
  __builtin_amdgcn_sched_barrier(0);
  // step 15: compute only
  compute_step(15, 1);

  float bs[4];
#pragma unroll
  for (int ct = 0; ct < 4; ++ct) bs[ct] = bias[16 * ct + l16];

  short* dstq = (mat == 0) ? qh : kh;
#pragma unroll
  for (int ct = 0; ct < 4; ++ct)
#pragma unroll
    for (int reg = 0; reg < 4; ++reg) {
      int r = row0 + 16 * w + quad * 4 + reg;
      int c = 16 * ct + l16;
      short hv = f2bf(acc[ct][reg] + bs[ct]);
      if (mat == 2)
        vhT[((size_t)(r >> 12) * DK_ + c) * S_ + (r & 4095)] = hv;
      else
        dstq[(size_t)r * DK_ + c] = hv;
    }
}

// ---------------------------------------------------------------------------
// Kernel 2: split-K flash attention, bf16 MFMA, transposed formulation.
// ---------------------------------------------------------------------------
__global__ __launch_bounds__(256) void attn_mfma(
    const short* __restrict__ qh, const short* __restrict__ kh,
    const short* __restrict__ vhT, const unsigned int* __restrict__ mbits,
    float* __restrict__ Opart, float* __restrict__ mpart,
    float* __restrict__ lpart, int ns) {
  __shared__ short ks[64][72];
  __shared__ short vt[64][72];
  __shared__ short ps[4][16][72];

  const int b = blockIdx.z;
  const int split = blockIdx.y;
  const int q0 = blockIdx.x * 64;
  const int t = threadIdx.x, lane = t & 63, w = t >> 6;
  const int quad = lane >> 4, l16 = lane & 15;
  const int myq = q0 + 16 * w + l16;

  const int kt0 = split * (S_ / ns);
  const int kt1 = kt0 + S_ / ns;

  bf16x8 qf[2];
  {
    const short* src = qh + ((size_t)b * S_ + myq) * DK_ + quad * 8;
    qf[0] = *(const bf16x8*)src;
    qf[1] = *(const bf16x8*)(src + 32);
  }

  f32x4 ao[4] = {};
  float m_i = -INFINITY, l_i = 0.0f;

  const int sr = t >> 2;        // staging row 0..63
  const int sseg = t & 3;       // 16B segments sseg, sseg+4

  for (int kt = kt0; kt < kt1; kt += 64) {
    __syncthreads();
    {
      const short* srck = kh + ((size_t)b * S_ + kt + sr) * DK_;
      *(bf16x8*)&ks[sr][8 * sseg]       = *(const bf16x8*)(srck + 8 * sseg);
      *(bf16x8*)&ks[sr][8 * (sseg + 4)] = *(const bf16x8*)(srck + 8 * (sseg + 4));
      const short* srcv = vhT + ((size_t)b * DK_ + sr) * S_ + kt;
      *(bf16x8*)&vt[sr][8 * sseg]       = *(const bf16x8*)(srcv + 8 * sseg);
      *(bf16x8*)&vt[sr][8 * (sseg + 4)] = *(const bf16x8*)(srcv + 8 * (sseg + 4));
    }
    const uint2 mw = *(const uint2*)&mbits[(size_t)myq * 128 + (kt >> 5)];
    __syncthreads();

    // S^T = K . Q^T
    f32x4 sacc[4] = {};
#pragma unroll
    for (int c = 0; c < 2; ++c)
#pragma unroll
      for (int tt = 0; tt < 4; ++tt) {
        bf16x8 a = *(const bf16x8*)&ks[16 * tt + l16][c * 32 + quad * 8];
        sacc[tt] = __builtin_amdgcn_mfma_f32_16x16x32_bf16(a, qf[c], sacc[tt], 0, 0, 0);
      }

    // mask + scale
    float sc[16];
#pragma unroll
    for (int tt = 0; tt < 4; ++tt) {
      unsigned wrd = (tt & 2) ? mw.y : mw.x;
      int base = (tt & 1) * 16 + quad * 4;
#pragma unroll
      for (int r = 0; r < 4; ++r)
        sc[tt * 4 + r] = ((wrd >> (base + r)) & 1) ? sacc[tt][r] * 0.125f : -1e9f;
    }

    // per-lane online softmax (lane owns one q-col)
    float mx = sc[0];
#pragma unroll
    for (int i = 1; i < 16; ++i) mx = fmaxf(mx, sc[i]);
    mx = fmaxf(mx, __shfl_xor(mx, 16));
    mx = fmaxf(mx, __shfl_xor(mx, 32));
    float m_new = fmaxf(m_i, mx);
    float alpha = __expf(m_i - m_new);   // first iter: exp(-inf)=0
    float p[16], sum = 0.0f;
#pragma unroll
    for (int i = 0; i < 16; ++i) { p[i] = __expf(sc[i] - m_new); sum += p[i]; }
    sum += __shfl_xor(sum, 16);
    sum += __shfl_xor(sum, 32);
    l_i = l_i * alpha + sum;
    m_i = m_new;

    // P^T -> LDS bf16
#pragma unroll
    for (int tt = 0; tt < 4; ++tt) {
      bf16x4 pk;
#pragma unroll
      for (int r = 0; r < 4; ++r) pk[r] = f2bf(p[tt * 4 + r]);
      *(bf16x4*)&ps[w][l16][16 * tt + quad * 4] = pk;
    }

#pragma unroll
    for (int dt = 0; dt < 4; ++dt)
#pragma unroll
      for (int r = 0; r < 4; ++r) ao[dt][r] *= alpha;

    // O^T += V^T . P^T
#pragma unroll
    for (int c = 0; c < 2; ++c) {
      bf16x8 bp = *(const bf16x8*)&ps[w][l16][c * 32 + quad * 8];
#pragma unroll
      for (int dt = 0; dt < 4; ++dt) {
        bf16x8 av = *(const bf16x8*)&vt[16 * dt + l16][c * 32 + quad * 8];
        ao[dt] = __builtin_amdgcn_mfma_f32_16x16x32_bf16(av, bp, ao[dt], 0, 0, 0);
      }
    }
  }

  const size_t prow = (size_t)split * NROW + (size_t)b * S_ + myq;
#pragma unroll
  for (int dt = 0; dt < 4; ++dt)
    *(f32x4*)&Opart[prow * DK_ + 16 * dt + quad * 4] = ao[dt];
  if (quad == 0) {
    mpart[prow] = m_i;
    lpart[prow] = l_i;
  }
}

// ---------------------------------------------------------------------------
// Kernel 2b: combine split partials -> o bf16.
// ---------------------------------------------------------------------------
__global__ __launch_bounds__(256) void attn_combine(
    const float* __restrict__ Opart, const float* __restrict__ mpart,
    const float* __restrict__ lpart, short* __restrict__ o_bf, int ns) {
  const int t = threadIdx.x;
  const int row = blockIdx.x * 64 + (t >> 2);
  const int c0 = (t & 3) * 16;

  float M = -INFINITY;
  for (int s = 0; s < ns; ++s) M = fmaxf(M, mpart[(size_t)s * NROW + row]);
  float L = 0.0f, wt[4];
  for (int s = 0; s < ns; ++s) {
    wt[s] = __expf(mpart[(size_t)s * NROW + row] - M);
    L += wt[s] * lpart[(size_t)s * NROW + row];
  }
  float acc[16] = {};
  for (int s = 0; s < ns; ++s) {
    const float* src = Opart + ((size_t)s * NROW + row) * DK_ + c0;
#pragma unroll
    for (int j = 0; j < 16; j += 4) {
      f32x4 vv = *(const f32x4*)(src + j);
#pragma unroll
      for (int r = 0; r < 4; ++r) acc[j + r] += wt[s] * vv[r];
    }
  }
  const float inv = 1.0f / L;
  bf16x8 o0, o1;
#pragma unroll
  for (int j = 0; j < 8; ++j) {
    o0[j] = f2bf(acc[j] * inv);
    o1[j] = f2bf(acc[j + 8] * inv);
  }
  *(bf16x8*)&o_bf[(size_t)row * DK_ + c0]     = o0;
  *(bf16x8*)&o_bf[(size_t)row * DK_ + c0 + 8] = o1;
}

// ---------------------------------------------------------------------------
// Kernel 3: output projection, bf16 MFMA.  Tile 64 s x 256 dm, K=64.
// ---------------------------------------------------------------------------
__global__ __launch_bounds__(256) void outproj_mfma(
    const short* __restrict__ o_bf, const float* __restrict__ Wo,
    const float* __restrict__ bo, float* __restrict__ out) {
  __shared__ short os[64][72];
  __shared__ short wos[256][72];

  const int t = threadIdx.x, lane = t & 63, w = t >> 6;
  const int quad = lane >> 4, l16 = lane & 15;
  const int s0 = blockIdx.y * 64;
  const int dm0 = blockIdx.x * 256;

  {  // stage o (bf16 copy)
    int r = t >> 2, cq = (t & 3) * 16;
    const short* src = o_bf + (size_t)(s0 + r) * DK_ + cq;
    *(bf16x8*)&os[r][cq]     = *(const bf16x8*)src;
    *(bf16x8*)&os[r][cq + 8] = *(const bf16x8*)(src + 8);
  }
#pragma unroll
  for (int pass = 0; pass < 4; ++pass) {  // stage Wo tile 256x64 fp32->bf16
    int r = pass * 64 + (t >> 2), cq = (t & 3) * 16;
    const float* src = Wo + (size_t)(dm0 + r) * DK_ + cq;
    f32x4 a0 = *(const f32x4*)src, a1 = *(const f32x4*)(src + 4);
    f32x4 a2 = *(const f32x4*)(src + 8), a3 = *(const f32x4*)(src + 12);
    bf16x8 v0, v1;
#pragma unroll
    for (int j = 0; j < 4; ++j) {
      v0[j] = f2bf(a0[j]); v0[j + 4] = f2bf(a1[j]);
      v1[j] = f2bf(a2[j]); v1[j + 4] = f2bf(a3[j]);
    }
    *(bf16x8*)&wos[r][cq]     = v0;
    *(bf16x8*)&wos[r][cq + 8] = v1;
  }
  __syncthreads();

  bf16x8 af[2];
#pragma unroll
  for (int c = 0; c < 2; ++c)
    af[c] = *(const bf16x8*)&os[16 * w + l16][c * 32 + quad * 8];

  f32x4 acc[16] = {};
#pragma unroll
  for (int c = 0; c < 2; ++c)
#pragma unroll
    for (int nt = 0; nt < 16; ++nt) {
      bf16x8 bw = *(const bf16x8*)&wos[16 * nt + l16][c * 32 + quad * 8];
      acc[nt] = __builtin_amdgcn_mfma_f32_16x16x32_bf16(af[c], bw, acc[nt], 0, 0, 0);
    }

  float bias_r[16];
#pragma unroll
  for (int nt = 0; nt < 16; ++nt) bias_r[nt] = bo[dm0 + 16 * nt + l16];

#pragma unroll
  for (int nt = 0; nt < 16; ++nt)
#pragma unroll
    for (int reg = 0; reg < 4; ++reg) {
      int s = s0 + 16 * w + quad * 4 + reg;
      int dm = dm0 + 16 * nt + l16;
      out[(size_t)s * DM_ + dm] = acc[nt][reg] + bias_r[nt];
    }
}

// ---------------------------------------------------------------------------
extern "C" void kernel_launch(void* const* d_in, const int* in_sizes, int n_in,
                              void* d_out, int out_size, void* d_ws,
                              size_t ws_size, hipStream_t stream) {
  (void)in_sizes; (void)n_in; (void)out_size;
  const float* q  = (const float*)d_in[0];
  const float* k  = (const float*)d_in[1];
  const float* v  = (const float*)d_in[2];
  const int* mask = (const int*)d_in[3];
  const float* Wq = (const float*)d_in[4];
  const float* bq = (const float*)d_in[5];
  const float* Wk = (const float*)d_in[6];
  const float* bk = (const float*)d_in[7];
  const float* Wv = (const float*)d_in[8];
  const float* bv = (const float*)d_in[9];
  const float* Wo = (const float*)d_in[10];
  const float* bo = (const float*)d_in[11];
  float* out = (float*)d_out;

  // ws layout: qh 2MB | kh 2MB | vhT 2MB | mbits 2MB | o_bf 2MB |
  //            mpart 256KB | lpart 256KB | Opart ns*4MB
  short* qh  = (short*)d_ws;
  short* kh  = qh + (size_t)NROW * DK_;
  short* vhT = kh + (size_t)NROW * DK_;
  unsigned int* mbits = (unsigned int*)(vhT + (size_t)NROW * DK_);
  short* o_bf = (short*)(mbits + (size_t)S_ * 128);
  float* mpart = (float*)(o_bf + (size_t)NROW * DK_);
  float* lpart = mpart + 4 * NROW;           // reserved for ns up to 4
  float* Opart = lpart + 4 * NROW;
  // Wbf (3 x 64 x 1024 bf16 = 384 KB) aliases the head of Opart: prep writes
  // it, proj reads it, and only AFTER proj does attn_mfma overwrite Opart.
  short* wbf = (short*)Opart;

  const size_t base_bytes = (size_t)((char*)Opart - (char*)d_ws);
  const size_t per_split = (size_t)NROW * DK_ * sizeof(float);   // 4 MB
  int ns = 1;
  if (ws_size >= base_bytes + 4 * per_split) ns = 4;
  else if (ws_size >= base_bytes + 2 * per_split) ns = 2;

  prep<<<1027, 256, 0, stream>>>(mask, (unsigned long long*)mbits,
                                 Wq, Wk, Wv, wbf);
  proj_mfma<<<dim3(NROW / 64, 1, 3), 256, 0, stream>>>(
      q, k, v, wbf, bq, bk, bv, qh, kh, vhT);
  attn_mfma<<<dim3(S_ / 64, ns, B_), 256, 0, stream>>>(
      qh, kh, vhT, mbits, Opart, mpart, lpart, ns);
  attn_combine<<<NROW / 64, 256, 0, stream>>>(Opart, mpart, lpart, o_bf, ns);
  outproj_mfma<<<dim3(DM_ / 256, NROW / 64), 256, 0, stream>>>(o_bf, Wo, bo, out);
}